// Round 11
// baseline (294.588 us; speedup 1.0000x reference)
//
#include <hip/hip_runtime.h>

#define B_   512
#define T_   365
#define DD_  5
#define DS_  27
#define H_   256
#define ROWS 2
#define NBLK (B_ / ROWS)      // 256 blocks = 1 per CU
#define NW   8
#define NTHR (NW * 64)        // 512 threads
#define HP   288              // h row pitch (f16): 576B -> row1 at bank +16

typedef _Float16 half8_t __attribute__((ext_vector_type(8)));
typedef float    f32x4   __attribute__((ext_vector_type(4)));

#define LOG2E_ 1.4426950408889634f

__device__ __forceinline__ float sigmoid_f(float x) {
    return __builtin_amdgcn_rcpf(1.0f + __builtin_amdgcn_exp2f(-x * LOG2E_));
}
__device__ __forceinline__ float tanh_f(float x) {
    return 1.0f - 2.0f * __builtin_amdgcn_rcpf(1.0f + __builtin_amdgcn_exp2f(2.0f * LOG2E_ * x));
}

__global__ __launch_bounds__(NTHR, 2)
void ealstm_kernel(const float* __restrict__ xdyn,   // [B,T,DD]
                   const float* __restrict__ xstat,  // [B,DS]
                   const float* __restrict__ Wi, const float* __restrict__ bi,
                   const float* __restrict__ Wf, const float* __restrict__ bf_,
                   const float* __restrict__ Wg, const float* __restrict__ bg,
                   const float* __restrict__ Wo, const float* __restrict__ bo,
                   const float* __restrict__ Wh, const float* __restrict__ bh,
                   float* __restrict__ out)
{
    const int tid = threadIdx.x;
    const int l   = tid & 63;
    const int w   = tid >> 6;
    const int b0  = blockIdx.x * ROWS;

    // h double-buffer: 2 real rows, 288-f16 pitch. Batch rows 0,1 feed MFMA
    // A-rows {0,4,8,12} (and, unmasked, every A-row m gets hbuf[(m>>2)&1] —
    // garbage C-rows m∉{0,4,8,12} are never read; C-row m depends only on
    // A-row m). C row = 4*(lane>>4)+reg, so acc reg 0 of lane group g holds
    // batch row g&1 — every lane owns its (row, col) element directly.
    __shared__ __align__(16) _Float16 hbuf[2][2][HP];
    __shared__ __align__(16) float xsh[ROWS][T_][8];   // padded stride-8
    __shared__ float red[2][NW];

    // zero h buffers
    {
        _Float16* hz = &hbuf[0][0][0];
        for (int i = tid; i < 2 * 2 * HP; i += NTHR) hz[i] = (_Float16)0.0f;
    }
    // preload x_dynamic (padded)
    for (int i = tid; i < ROWS * T_ * DD_; i += NTHR) {
        int r   = i / (T_ * DD_);
        int rem = i - r * (T_ * DD_);
        int tt  = rem / DD_;
        int d   = rem - tt * DD_;
        xsh[r][tt][d] = xdyn[(size_t)(b0 + r) * (T_ * DD_) + rem];
    }

    // ---- persistent B fragments (fp16, MFMA 16x16x32 layout), wave w: cols [w*32, w*32+32)
    const int colW = w * 32;
    const int lg   = l >> 4;
    const int lm   = l & 15;
    half8_t Bf[2][2][8];      // 32 half8 = 128 regs
    {
#pragma unroll
        for (int m = 0; m < 2; ++m) {
            const float* Ws = (m == 0) ? Wg : Wo;
#pragma unroll
            for (int tt = 0; tt < 2; ++tt) {
#pragma unroll
                for (int ks = 0; ks < 8; ++ks) {
                    int col = colW + tt * 16 + lm;
                    int k   = ks * 32 + 8 * lg;
                    const float* p = Ws + (size_t)(DD_ + k) * H_ + col;
                    half8_t v;
#pragma unroll
                    for (int i = 0; i < 8; ++i) v[i] = (_Float16)p[(size_t)i * H_];
                    Bf[m][tt][ks] = v;
                }
            }
        }
    }

    // ---- per-lane ownership: lane l -> (row r_l, col c_l)
    const int r_l = (l >> 4) & 1;
    const int c_l = colW + (l >> 5) * 16 + lm;

    float Wgx[DD_], Wox[DD_];
#pragma unroll
    for (int d = 0; d < DD_; ++d) {
        Wgx[d] = Wg[d * H_ + c_l];
        Wox[d] = Wo[d * H_ + c_l];
    }
    const float bgv = bg[c_l], bov = bo[c_l];

    float iG, fG, cst = 0.0f;
    {
        float ai = bi[c_l], af = bf_[c_l];
        for (int d = 0; d < DS_; ++d) {
            float xv = xstat[(b0 + r_l) * DS_ + d];
            ai += xv * Wi[d * H_ + c_l];
            af += xv * Wf[d * H_ + c_l];
        }
        iG = sigmoid_f(ai);
        fG = sigmoid_f(af);
    }

    const int  arow = (lm >> 2) & 1;     // A-row m -> batch row (m>>2)&1
    const bool low  = (l < 32);          // which acc holds this lane's element

    half8_t Af[8];

    __syncthreads();

#pragma unroll 2
    for (int t = 0; t < T_; ++t) {
        const int cur = t & 1;
        const int nxt = cur ^ 1;

        // A fragments — all 64 lanes (8 lanes share each address -> broadcast)
#pragma unroll
        for (int ks = 0; ks < 8; ++ks)
            Af[ks] = *(const half8_t*)&hbuf[cur][arow][ks * 32 + 8 * lg];

        // per-lane x-part (h-independent, hides Af latency)
        const float4 xv = *(const float4*)&xsh[r_l][t][0];
        const float  x4 = xsh[r_l][t][4];
        float xg = bgv + xv.x*Wgx[0] + xv.y*Wgx[1] + xv.z*Wgx[2] + xv.w*Wgx[3] + x4*Wgx[4];
        float xo = bov + xv.x*Wox[0] + xv.y*Wox[1] + xv.z*Wox[2] + xv.w*Wox[3] + x4*Wox[4];

        // acc C-init carries the x-part in the lane's own reg-0 slot
        f32x4 accG0 = {low ? xg : 0.f, 0.f, 0.f, 0.f};
        f32x4 accG1 = {low ? 0.f : xg, 0.f, 0.f, 0.f};
        f32x4 accO0 = {low ? xo : 0.f, 0.f, 0.f, 0.f};
        f32x4 accO1 = {low ? 0.f : xo, 0.f, 0.f, 0.f};
#pragma unroll
        for (int ks = 0; ks < 8; ++ks) {
            accG0 = __builtin_amdgcn_mfma_f32_16x16x32_f16(Af[ks], Bf[0][0][ks], accG0, 0, 0, 0);
            accG1 = __builtin_amdgcn_mfma_f32_16x16x32_f16(Af[ks], Bf[0][1][ks], accG1, 0, 0, 0);
            accO0 = __builtin_amdgcn_mfma_f32_16x16x32_f16(Af[ks], Bf[1][0][ks], accO0, 0, 0, 0);
            accO1 = __builtin_amdgcn_mfma_f32_16x16x32_f16(Af[ks], Bf[1][1][ks], accO1, 0, 0, 0);
        }

        // shuffle-free epilogue: every lane owns its value in reg 0
        float pg = low ? accG0[0] : accG1[0];
        float po = low ? accO0[0] : accO1[0];

        float g = tanh_f(pg);
        float o = sigmoid_f(po);
        cst = fG * cst + iG * g;
        float hv = o * tanh_f(cst);
        hbuf[nxt][r_l][c_l] = (_Float16)hv;

        __syncthreads();
    }

    // ---- output: out[b] = sum_c h[b][c] * Wh[c] + bh ----
    const int fin  = T_ & 1;
    const int oc   = tid & 255;
    const int orow = tid >> 8;
    float v = (float)hbuf[fin][orow][oc] * Wh[oc];
#pragma unroll
    for (int off = 32; off > 0; off >>= 1)
        v += __shfl_down(v, off);
    if (l == 0) red[orow][w & 3] = v;
    __syncthreads();
    if (tid < ROWS) {
        out[b0 + tid] = red[tid][0] + red[tid][1] + red[tid][2] + red[tid][3] + bh[0];
    }
}

extern "C" void kernel_launch(void* const* d_in, const int* in_sizes, int n_in,
                              void* d_out, int out_size, void* d_ws, size_t ws_size,
                              hipStream_t stream) {
    (void)in_sizes; (void)n_in; (void)out_size; (void)d_ws; (void)ws_size;
    const float* xdyn  = (const float*)d_in[0];
    const float* xstat = (const float*)d_in[1];
    const float* Wi    = (const float*)d_in[2];
    const float* bi    = (const float*)d_in[3];
    const float* Wf    = (const float*)d_in[4];
    const float* bf    = (const float*)d_in[5];
    const float* Wg    = (const float*)d_in[6];
    const float* bg    = (const float*)d_in[7];
    const float* Wo    = (const float*)d_in[8];
    const float* bo    = (const float*)d_in[9];
    const float* Wh    = (const float*)d_in[10];
    const float* bh    = (const float*)d_in[11];
    float* out = (float*)d_out;

    hipLaunchKernelGGL(ealstm_kernel, dim3(NBLK), dim3(NTHR), 0, stream,
                       xdyn, xstat, Wi, bi, Wf, bf, Wg, bg, Wo, bo, Wh, bh, out);
}

// Round 12
// 263.209 us; speedup vs baseline: 1.1192x; 1.1192x over previous
//
#include <hip/hip_runtime.h>

#define B_   512
#define T_   365
#define DD_  5
#define DS_  27
#define H_   256
#define ROWS 2
#define NBLK (B_ / ROWS)      // 256 blocks = 1 per CU
#define NW   8
#define NTHR (NW * 64)        // 512 threads
#define HP   288              // h row pitch (f16): 576B -> row1 at bank +16

typedef _Float16 half8_t __attribute__((ext_vector_type(8)));
typedef float    f32x4   __attribute__((ext_vector_type(4)));

#define LOG2E_ 1.4426950408889634f

__device__ __forceinline__ float sigmoid_f(float x) {
    return __builtin_amdgcn_rcpf(1.0f + __builtin_amdgcn_exp2f(-x * LOG2E_));
}
__device__ __forceinline__ float tanh_f(float x) {
    return 1.0f - 2.0f * __builtin_amdgcn_rcpf(1.0f + __builtin_amdgcn_exp2f(2.0f * LOG2E_ * x));
}

__global__ __launch_bounds__(NTHR, 2)
void ealstm_kernel(const float* __restrict__ xdyn,   // [B,T,DD]
                   const float* __restrict__ xstat,  // [B,DS]
                   const float* __restrict__ Wi, const float* __restrict__ bi,
                   const float* __restrict__ Wf, const float* __restrict__ bf_,
                   const float* __restrict__ Wg, const float* __restrict__ bg,
                   const float* __restrict__ Wo, const float* __restrict__ bo,
                   const float* __restrict__ Wh, const float* __restrict__ bh,
                   float* __restrict__ out)
{
    const int tid = threadIdx.x;
    const int l   = tid & 63;
    const int w   = tid >> 6;
    const int b0  = blockIdx.x * ROWS;

    // h double-buffer: 2 real rows, 288-f16 pitch. Batch rows 0,1 feed MFMA
    // A-rows {0,4,8,12} = {r0,r1,r0,r1} (lanes lm∈{0,4,8,12}; duplicates are
    // same-address broadcasts). C row = 4*(lane>>4)+reg, so acc reg 0 of lane
    // group g holds batch row g&1 — every lane owns its (row,col) element
    // directly; no cross-lane epilogue traffic.
    __shared__ __align__(16) _Float16 hbuf[2][2][HP];
    __shared__ __align__(16) float xsh[ROWS][T_][8];   // padded stride-8
    __shared__ float red[2][NW];

    // zero h buffers
    {
        _Float16* hz = &hbuf[0][0][0];
        for (int i = tid; i < 2 * 2 * HP; i += NTHR) hz[i] = (_Float16)0.0f;
    }
    // preload x_dynamic (padded)
    for (int i = tid; i < ROWS * T_ * DD_; i += NTHR) {
        int r   = i / (T_ * DD_);
        int rem = i - r * (T_ * DD_);
        int tt  = rem / DD_;
        int d   = rem - tt * DD_;
        xsh[r][tt][d] = xdyn[(size_t)(b0 + r) * (T_ * DD_) + rem];
    }

    // ---- persistent B fragments (fp16, MFMA 16x16x32 layout), wave w: cols [w*32, w*32+32)
    const int colW = w * 32;
    const int lg   = l >> 4;
    const int lm   = l & 15;
    half8_t Bf[2][2][8];      // 32 half8 = 128 regs
    {
#pragma unroll
        for (int m = 0; m < 2; ++m) {
            const float* Ws = (m == 0) ? Wg : Wo;
#pragma unroll
            for (int tt = 0; tt < 2; ++tt) {
#pragma unroll
                for (int ks = 0; ks < 8; ++ks) {
                    int col = colW + tt * 16 + lm;
                    int k   = ks * 32 + 8 * lg;
                    const float* p = Ws + (size_t)(DD_ + k) * H_ + col;
                    half8_t v;
#pragma unroll
                    for (int i = 0; i < 8; ++i) v[i] = (_Float16)p[(size_t)i * H_];
                    Bf[m][tt][ks] = v;
                }
            }
        }
    }

    // ---- per-lane ownership: lane l -> (row r_l, col c_l)
    const int r_l = (l >> 4) & 1;
    const int c_l = colW + (l >> 5) * 16 + lm;

    float Wgx[DD_], Wox[DD_];
#pragma unroll
    for (int d = 0; d < DD_; ++d) {
        Wgx[d] = Wg[d * H_ + c_l];
        Wox[d] = Wo[d * H_ + c_l];
    }
    const float bgv = bg[c_l], bov = bo[c_l];

    float iG, fG, cst = 0.0f;
    {
        float ai = bi[c_l], af = bf_[c_l];
        for (int d = 0; d < DS_; ++d) {
            float xv = xstat[(b0 + r_l) * DS_ + d];
            ai += xv * Wi[d * H_ + c_l];
            af += xv * Wf[d * H_ + c_l];
        }
        iG = sigmoid_f(ai);
        fG = sigmoid_f(af);
    }

    half8_t Af[8];
    {
        half8_t z;
#pragma unroll
        for (int i = 0; i < 8; ++i) z[i] = (_Float16)0.0f;
#pragma unroll
        for (int ks = 0; ks < 8; ++ks) Af[ks] = z;
    }
    const bool areal = ((lm & 3) == 0);   // A-rows 0,4,8,12
    const int  arow  = (lm >> 2) & 1;     // -> batch rows 0,1,0,1
    const bool low   = (l < 32);

    __syncthreads();

    // x-part software pipeline: xg/xo for step t are computed during step t-1.
    float xg, xo;
    {
        const float4 xv = *(const float4*)&xsh[r_l][0][0];
        const float  x4 = xsh[r_l][0][4];
        xg = bgv + xv.x*Wgx[0] + xv.y*Wgx[1] + xv.z*Wgx[2] + xv.w*Wgx[3] + x4*Wgx[4];
        xo = bov + xv.x*Wox[0] + xv.y*Wox[1] + xv.z*Wox[2] + xv.w*Wox[3] + x4*Wox[4];
    }

#pragma unroll 2
    for (int t = 0; t < T_; ++t) {
        const int cur = t & 1;
        const int nxt = cur ^ 1;

        // A fragments (4 lanes per 16-group; duplicates broadcast)
        if (areal) {
#pragma unroll
            for (int ks = 0; ks < 8; ++ks)
                Af[ks] = *(const half8_t*)&hbuf[cur][arow][ks * 32 + 8 * lg];
        }

        // issue NEXT step's x loads now; they return during the burst
        const int tn = (t + 1 < T_) ? t + 1 : t;
        const float4 xvn = *(const float4*)&xsh[r_l][tn][0];
        const float  x4n = xsh[r_l][tn][4];

        f32x4 accG0 = {0.f,0.f,0.f,0.f}, accG1 = {0.f,0.f,0.f,0.f};
        f32x4 accO0 = {0.f,0.f,0.f,0.f}, accO1 = {0.f,0.f,0.f,0.f};
        __builtin_amdgcn_s_setprio(1);
#pragma unroll
        for (int ks = 0; ks < 8; ++ks) {
            accG0 = __builtin_amdgcn_mfma_f32_16x16x32_f16(Af[ks], Bf[0][0][ks], accG0, 0, 0, 0);
            accG1 = __builtin_amdgcn_mfma_f32_16x16x32_f16(Af[ks], Bf[0][1][ks], accG1, 0, 0, 0);
            accO0 = __builtin_amdgcn_mfma_f32_16x16x32_f16(Af[ks], Bf[1][0][ks], accO0, 0, 0, 0);
            accO1 = __builtin_amdgcn_mfma_f32_16x16x32_f16(Af[ks], Bf[1][1][ks], accO1, 0, 0, 0);
        }
        __builtin_amdgcn_s_setprio(0);

        // shuffle-free epilogue: every lane owns its value in reg 0
        float pg = (low ? accG0[0] : accG1[0]) + xg;
        float po = (low ? accO0[0] : accO1[0]) + xo;

        float g = tanh_f(pg);
        float o = sigmoid_f(po);
        cst = fG * cst + iG * g;
        float hv = o * tanh_f(cst);
        hbuf[nxt][r_l][c_l] = (_Float16)hv;

        // next step's x-part (independent of the gate chain; fills issue gaps)
        xg = bgv + xvn.x*Wgx[0] + xvn.y*Wgx[1] + xvn.z*Wgx[2] + xvn.w*Wgx[3] + x4n*Wgx[4];
        xo = bov + xvn.x*Wox[0] + xvn.y*Wox[1] + xvn.z*Wox[2] + xvn.w*Wox[3] + x4n*Wox[4];

        __syncthreads();
    }

    // ---- output: out[b] = sum_c h[b][c] * Wh[c] + bh ----
    const int fin  = T_ & 1;
    const int oc   = tid & 255;
    const int orow = tid >> 8;
    float v = (float)hbuf[fin][orow][oc] * Wh[oc];
#pragma unroll
    for (int off = 32; off > 0; off >>= 1)
        v += __shfl_down(v, off);
    if (l == 0) red[orow][w & 3] = v;
    __syncthreads();
    if (tid < ROWS) {
        out[b0 + tid] = red[tid][0] + red[tid][1] + red[tid][2] + red[tid][3] + bh[0];
    }
}

extern "C" void kernel_launch(void* const* d_in, const int* in_sizes, int n_in,
                              void* d_out, int out_size, void* d_ws, size_t ws_size,
                              hipStream_t stream) {
    (void)in_sizes; (void)n_in; (void)out_size; (void)d_ws; (void)ws_size;
    const float* xdyn  = (const float*)d_in[0];
    const float* xstat = (const float*)d_in[1];
    const float* Wi    = (const float*)d_in[2];
    const float* bi    = (const float*)d_in[3];
    const float* Wf    = (const float*)d_in[4];
    const float* bf    = (const float*)d_in[5];
    const float* Wg    = (const float*)d_in[6];
    const float* bg    = (const float*)d_in[7];
    const float* Wo    = (const float*)d_in[8];
    const float* bo    = (const float*)d_in[9];
    const float* Wh    = (const float*)d_in[10];
    const float* bh    = (const float*)d_in[11];
    float* out = (float*)d_out;

    hipLaunchKernelGGL(ealstm_kernel, dim3(NBLK), dim3(NTHR), 0, stream,
                       xdyn, xstat, Wi, bi, Wf, bf, Wg, bg, Wo, bo, Wh, bh, out);
}